// Round 4
// baseline (220.391 us; speedup 1.0000x reference)
//
#include <hip/hip_runtime.h>
#include <hip/hip_bf16.h>

using u16 = unsigned short;
typedef __attribute__((ext_vector_type(8))) short short8;   // 8 bf16 = 4 VGPR
typedef __attribute__((ext_vector_type(4))) float f32x4;

constexpr int Bc = 2, Sc = 1024, Ec = 1024, Hc = 16, HDc = 64;
constexpr float SCALE = 0.125f; // HD^-0.5

// f32 -> bf16 round-to-nearest-even
__device__ __forceinline__ u16 f2bf(float f) {
    union { float f; unsigned u; } v{f};
    unsigned r = v.u + 0x7FFF + ((v.u >> 16) & 1);
    return (u16)(r >> 16);
}

// ---------------------------------------------------------------------------
// P0b: V (B,H,S,HD panels) -> Vt[bh][d=64][S=1024] bf16 (transposed).
// grid (S/64, B*H), block 256.
// ---------------------------------------------------------------------------
__global__ __launch_bounds__(256) void k_convT(const float* __restrict__ V,
                                               u16* __restrict__ Vt) {
    __shared__ float tile[64][65];
    const int bh = blockIdx.y;
    const int k0 = blockIdx.x * 64;
    const float* Vp = V + (size_t)bh * Sc * HDc + (size_t)k0 * HDc;
    const int tid = threadIdx.x;

    #pragma unroll
    for (int it = 0; it < 4; ++it) {
        int idx = tid + it * 256;
        int k = idx >> 4, d4 = idx & 15;
        float4 v = *(const float4*)&Vp[k * HDc + d4 * 4];
        tile[d4 * 4 + 0][k] = v.x;
        tile[d4 * 4 + 1][k] = v.y;
        tile[d4 * 4 + 2][k] = v.z;
        tile[d4 * 4 + 3][k] = v.w;
    }
    __syncthreads();

    u16* Op = Vt + (size_t)bh * HDc * Sc + k0;
    #pragma unroll
    for (int it = 0; it < 4; ++it) {
        int idx = tid + it * 256;
        int d = idx >> 4, kq = idx & 15;
        u16 t[4];
        #pragma unroll
        for (int j = 0; j < 4; ++j) t[j] = f2bf(tile[d][kq * 4 + j]);
        *(uint2*)&Op[(size_t)d * Sc + kq * 4] = *(uint2*)t;
    }
}

// ---------------------------------------------------------------------------
// K1: scores + aid-mixer -> pre (f32). MFMA 16x16x32 bf16.
// Grid 2048 (1D): bid = xcd + 8*h + 128*tgrp so the 16 h-siblings of one
// (b,qt,kt) tile land on the SAME XCD -> aid tile is L2-shared 16x.
// block 256 = 4 waves, each computes a 64x64 quadrant of the 128x128 tile.
// Epilogue retiles acc through LDS so aid reads and pre writes are float4.
// ---------------------------------------------------------------------------
__global__ __launch_bounds__(256, 2) void k_scores(
    const float* __restrict__ Qf, const float* __restrict__ Kf,
    const float* __restrict__ aid, const float* __restrict__ mw,
    const float* __restrict__ mb, const float* __restrict__ ascale,
    float* __restrict__ pre)
{
    __shared__ u16 smem[2 * 128 * 64];        // Qs | Ks ; aliased as Rt later
    u16* Qs = smem;
    u16* Ks = smem + 128 * 64;

    const int bid = blockIdx.x;               // 0..2047
    const int xcd  = bid & 7;
    const int h    = (bid >> 3) & 15;
    const int tidx = (bid >> 7) * 8 + xcd;    // 0..127 = (b,qt,kt)
    const int kt = tidx & 7;
    const int qt = (tidx >> 3) & 7;
    const int b  = tidx >> 6;

    const float* Qp = Qf + (size_t)(b * Hc + h) * Sc * HDc + (size_t)qt * 128 * HDc;
    const float* Kp = Kf + (size_t)(b * Hc + h) * Sc * HDc + (size_t)kt * 128 * HDc;

    const int tid = threadIdx.x;

    // stage 128x64 tiles, f32 -> bf16, 16B granules, XOR swizzle g^(r&7)
    #pragma unroll
    for (int it = 0; it < 4; ++it) {
        int idx = tid + it * 256;
        int r = idx >> 3, g = idx & 7;
        int gs = g ^ (r & 7);
        const float* qs = Qp + r * 64 + g * 8;
        const float* ks = Kp + r * 64 + g * 8;
        float4 qa = *(const float4*)qs, qb = *(const float4*)(qs + 4);
        float4 ka = *(const float4*)ks, kb2 = *(const float4*)(ks + 4);
        u16 tq[8] = {f2bf(qa.x), f2bf(qa.y), f2bf(qa.z), f2bf(qa.w),
                     f2bf(qb.x), f2bf(qb.y), f2bf(qb.z), f2bf(qb.w)};
        u16 tk[8] = {f2bf(ka.x), f2bf(ka.y), f2bf(ka.z), f2bf(ka.w),
                     f2bf(kb2.x), f2bf(kb2.y), f2bf(kb2.z), f2bf(kb2.w)};
        *(short8*)&Qs[r * 64 + gs * 8] = *(short8*)tq;
        *(short8*)&Ks[r * 64 + gs * 8] = *(short8*)tk;
    }
    __syncthreads();

    const int w = tid >> 6, lane = tid & 63;
    const int wq = (w >> 1) * 64, wk = (w & 1) * 64;
    const int lrow = lane & 15, lhi = lane >> 4;

    f32x4 acc[4][4] = {};
    #pragma unroll
    for (int ks = 0; ks < 2; ++ks) {
        short8 af[4], bfr[4];
        #pragma unroll
        for (int f = 0; f < 4; ++f) {
            int rq = wq + f * 16 + lrow;
            int g  = ks * 4 + lhi;
            af[f]  = *(const short8*)&Qs[rq * 64 + (g ^ (rq & 7)) * 8];
            int rk = wk + f * 16 + lrow;
            bfr[f] = *(const short8*)&Ks[rk * 64 + (g ^ (rk & 7)) * 8];
        }
        #pragma unroll
        for (int fq = 0; fq < 4; ++fq)
            #pragma unroll
            for (int fk = 0; fk < 4; ++fk)
                acc[fq][fk] = __builtin_amdgcn_mfma_f32_16x16x32_bf16(
                    af[fq], bfr[fk], acc[fq][fk], 0, 0, 0);
    }

    const float w0 = mw[h * 4 + 0], w1 = mw[h * 4 + 1];
    const float w2 = mw[h * 4 + 2], w3 = mw[h * 4 + 3];
    const float bias = mb[h];
    const float asc  = ascale[0];
    const size_t prebase = (size_t)(b * Hc + h) * Sc * Sc;

    // Retile buffer aliases the (now dead) Qs/Ks: 32 rows x 132 f32 = 16.5 KB
    float* Rt = (float*)smem;

    #pragma unroll
    for (int fq = 0; fq < 4; ++fq) {
        __syncthreads();   // Rt reads of prev iter done / LDS tiles dead (fq=0)
        #pragma unroll
        for (int r = 0; r < 4; ++r)
            #pragma unroll
            for (int fk = 0; fk < 4; ++fk)
                Rt[((w >> 1) * 16 + lhi * 4 + r) * 132 + wk + fk * 16 + lrow] =
                    acc[fq][fk][r];
        __syncthreads();

        const int rib = tid >> 3;             // 0..31
        const int c0  = (tid & 7) * 16;       // 0..112
        float s16[16];
        #pragma unroll
        for (int i = 0; i < 4; ++i)
            *(float4*)&s16[i * 4] = *(const float4*)&Rt[rib * 132 + c0 + i * 4];

        const int q  = qt * 128 + (rib >> 4) * 64 + fq * 16 + (rib & 15);
        const int kb = kt * 128 + c0;
        const float* ap = aid + ((size_t)(b * Sc + q) * Sc + kb) * 3;
        float a48[48];
        #pragma unroll
        for (int i = 0; i < 12; ++i)
            *(float4*)&a48[i * 4] = *(const float4*)&ap[i * 4];

        float o[16];
        #pragma unroll
        for (int j = 0; j < 16; ++j) {
            float s = s16[j] * SCALE;
            float m = s * w0 + a48[j * 3] * w1 + a48[j * 3 + 1] * w2
                    + a48[j * 3 + 2] * w3 + bias;
            o[j] = s + fmaxf(m, 0.f) * asc;
        }
        float* dst = pre + prebase + (size_t)q * Sc + kb;
        #pragma unroll
        for (int i = 0; i < 4; ++i)
            *(float4*)&dst[i * 4] = *(const float4*)&o[i * 4];
    }
}

// ---------------------------------------------------------------------------
// K2: row softmax (f32 in/out). One wave per row. grid B*H*S/4, block 256.
// ---------------------------------------------------------------------------
__global__ __launch_bounds__(256) void k_softmax(
    const float* __restrict__ pre, float* __restrict__ attn)
{
    const int row  = blockIdx.x * 4 + (threadIdx.x >> 6);
    const int lane = threadIdx.x & 63;

    const float* src = pre + (size_t)row * Sc;
    float v[4][4];
    float m = -1e30f;
    #pragma unroll
    for (int i = 0; i < 4; ++i) {
        *(float4*)v[i] = *(const float4*)&src[lane * 4 + i * 256];
        #pragma unroll
        for (int j = 0; j < 4; ++j) m = fmaxf(m, v[i][j]);
    }
    #pragma unroll
    for (int off = 32; off; off >>= 1) m = fmaxf(m, __shfl_xor(m, off));

    float sum = 0.f;
    #pragma unroll
    for (int i = 0; i < 4; ++i)
        #pragma unroll
        for (int j = 0; j < 4; ++j) {
            v[i][j] = __expf(v[i][j] - m);
            sum += v[i][j];
        }
    #pragma unroll
    for (int off = 32; off; off >>= 1) sum += __shfl_xor(sum, off);

    const float inv = 1.f / sum;
    float* dst = attn + (size_t)row * Sc;
    #pragma unroll
    for (int i = 0; i < 4; ++i) {
        float4 o = make_float4(v[i][0] * inv, v[i][1] * inv, v[i][2] * inv, v[i][3] * inv);
        *(float4*)&dst[lane * 4 + i * 256] = o;
    }
}

// ---------------------------------------------------------------------------
// K3: Omid(bf16) = attn @ V. A = attn (f32->bf16 at staging), B = Vt[d][k].
// grid (S/128, B*H), block 256 = 4 waves; wave = 32 q-rows x 64 d.
// ---------------------------------------------------------------------------
__global__ __launch_bounds__(256, 2) void k_pv(
    const float* __restrict__ attn, const u16* __restrict__ Vt,
    u16* __restrict__ Omid)
{
    __shared__ u16 As[128 * 64];
    __shared__ u16 Vs[64 * 64];

    const int bh = blockIdx.y;
    const int b  = bh >> 4, h = bh & 15;
    const int qt = blockIdx.x * 128;

    const float* Ab = attn + ((size_t)bh * Sc + qt) * Sc;
    const u16*   Vp = Vt + (size_t)bh * HDc * Sc;

    const int tid = threadIdx.x;
    const int w = tid >> 6, lane = tid & 63;
    const int lrow = lane & 15, lhi = lane >> 4;

    f32x4 acc[2][4] = {};

    for (int kb = 0; kb < Sc; kb += 64) {
        #pragma unroll
        for (int it = 0; it < 4; ++it) {
            int idx = tid + it * 256;
            int r = idx >> 3, g = idx & 7;
            const float* srcp = Ab + (size_t)r * Sc + kb + g * 8;
            float4 a = *(const float4*)srcp;
            float4 c = *(const float4*)(srcp + 4);
            u16 t[8] = {f2bf(a.x), f2bf(a.y), f2bf(a.z), f2bf(a.w),
                        f2bf(c.x), f2bf(c.y), f2bf(c.z), f2bf(c.w)};
            *(short8*)&As[r * 64 + (g ^ (r & 7)) * 8] = *(short8*)t;
        }
        #pragma unroll
        for (int it = 0; it < 2; ++it) {
            int idx = tid + it * 256;
            int r = idx >> 3, g = idx & 7;
            *(short8*)&Vs[r * 64 + (g ^ (r & 7)) * 8] =
                *(const short8*)&Vp[(size_t)r * Sc + kb + g * 8];
        }
        __syncthreads();

        #pragma unroll
        for (int ks = 0; ks < 2; ++ks) {
            short8 af[2], bfr[4];
            int g = ks * 4 + lhi;
            #pragma unroll
            for (int fq = 0; fq < 2; ++fq) {
                int rq = w * 32 + fq * 16 + lrow;
                af[fq] = *(const short8*)&As[rq * 64 + (g ^ (rq & 7)) * 8];
            }
            #pragma unroll
            for (int fd = 0; fd < 4; ++fd) {
                int rv = fd * 16 + lrow;
                bfr[fd] = *(const short8*)&Vs[rv * 64 + (g ^ (rv & 7)) * 8];
            }
            #pragma unroll
            for (int fq = 0; fq < 2; ++fq)
                #pragma unroll
                for (int fd = 0; fd < 4; ++fd)
                    acc[fq][fd] = __builtin_amdgcn_mfma_f32_16x16x32_bf16(
                        af[fq], bfr[fd], acc[fq][fd], 0, 0, 0);
        }
        __syncthreads();
    }

    #pragma unroll
    for (int fq = 0; fq < 2; ++fq)
        #pragma unroll
        for (int r = 0; r < 4; ++r) {
            const int q = qt + w * 32 + fq * 16 + lhi * 4 + r;
            u16* orow = Omid + ((size_t)b * Sc + q) * Ec + h * HDc;
            #pragma unroll
            for (int fd = 0; fd < 4; ++fd)
                orow[fd * 16 + lrow] = f2bf(acc[fq][fd][r]);
        }
}

// ---------------------------------------------------------------------------
// K4: out = Omid @ Wo^T + bo (f32 out). A = Omid bf16, B = Wo f32->bf16.
// 1D grid 256: mt = (bid>>4)*128, et = (bid&15)*64. block 256 = 4 waves.
// ---------------------------------------------------------------------------
__global__ __launch_bounds__(256, 2) void k_proj(
    const u16* __restrict__ Ob, const float* __restrict__ Wof,
    const float* __restrict__ bo, float* __restrict__ out)
{
    __shared__ u16 Xs[128 * 64];
    __shared__ u16 Ws[64 * 64];

    const int bid = blockIdx.x;
    const int mt = (bid >> 4) * 128;
    const int et = (bid & 15) * 64;

    const int tid = threadIdx.x;
    const int w = tid >> 6, lane = tid & 63;
    const int lrow = lane & 15, lhi = lane >> 4;

    f32x4 acc[2][4] = {};

    for (int kb = 0; kb < Ec; kb += 64) {
        #pragma unroll
        for (int it = 0; it < 4; ++it) {
            int idx = tid + it * 256;
            int r = idx >> 3, g = idx & 7;
            *(short8*)&Xs[r * 64 + (g ^ (r & 7)) * 8] =
                *(const short8*)&Ob[(size_t)(mt + r) * Ec + kb + g * 8];
        }
        #pragma unroll
        for (int it = 0; it < 2; ++it) {
            int idx = tid + it * 256;
            int r = idx >> 3, g = idx & 7;
            const float* sp = &Wof[(size_t)(et + r) * Ec + kb + g * 8];
            float4 x = *(const float4*)sp, y = *(const float4*)(sp + 4);
            u16 t[8] = {f2bf(x.x), f2bf(x.y), f2bf(x.z), f2bf(x.w),
                        f2bf(y.x), f2bf(y.y), f2bf(y.z), f2bf(y.w)};
            *(short8*)&Ws[r * 64 + (g ^ (r & 7)) * 8] = *(short8*)t;
        }
        __syncthreads();

        #pragma unroll
        for (int ks = 0; ks < 2; ++ks) {
            short8 af[2], bfr[4];
            int g = ks * 4 + lhi;
            #pragma unroll
            for (int fq = 0; fq < 2; ++fq) {
                int rq = w * 32 + fq * 16 + lrow;
                af[fq] = *(const short8*)&Xs[rq * 64 + (g ^ (rq & 7)) * 8];
            }
            #pragma unroll
            for (int fd = 0; fd < 4; ++fd) {
                int rv = fd * 16 + lrow;
                bfr[fd] = *(const short8*)&Ws[rv * 64 + (g ^ (rv & 7)) * 8];
            }
            #pragma unroll
            for (int fq = 0; fq < 2; ++fq)
                #pragma unroll
                for (int fd = 0; fd < 4; ++fd)
                    acc[fq][fd] = __builtin_amdgcn_mfma_f32_16x16x32_bf16(
                        af[fq], bfr[fd], acc[fq][fd], 0, 0, 0);
        }
        __syncthreads();
    }

    #pragma unroll
    for (int fq = 0; fq < 2; ++fq)
        #pragma unroll
        for (int r = 0; r < 4; ++r) {
            const int m = mt + w * 32 + fq * 16 + lhi * 4 + r;
            float* orow = out + (size_t)m * Ec + et;
            #pragma unroll
            for (int fd = 0; fd < 4; ++fd) {
                int e = fd * 16 + lrow;
                orow[e] = acc[fq][fd][r] + bo[et + e];
            }
        }
}

// ---------------------------------------------------------------------------
extern "C" void kernel_launch(void* const* d_in, const int* in_sizes, int n_in,
                              void* d_out, int out_size, void* d_ws, size_t ws_size,
                              hipStream_t stream) {
    const float* query  = (const float*)d_in[0];
    const float* key    = (const float*)d_in[1];
    const float* value  = (const float*)d_in[2];
    const float* aid    = (const float*)d_in[3];
    const float* mw     = (const float*)d_in[4];
    const float* mb     = (const float*)d_in[5];
    const float* Wo     = (const float*)d_in[6];
    const float* bo     = (const float*)d_in[7];
    const float* ascale = (const float*)d_in[8];

    float* out_p  = (float*)d_out;                       // (B,S,E)
    float* attn_p = out_p + (size_t)Bc * Sc * Ec;        // (B,H,S,S)
    float* pre_p  = attn_p + (size_t)Bc * Hc * Sc * Sc;  // (B,H,S,S)

    u16* Vtb  = (u16*)d_ws;                      // 2M elems (transposed V)
    u16* Omid = Vtb + (size_t)2 * 1024 * 1024;   // 2M elems

    k_convT<<<dim3(Sc / 64, Bc * Hc), 256, 0, stream>>>(value, Vtb);
    k_scores<<<2048, 256, 0, stream>>>(query, key, aid, mw, mb, ascale, pre_p);
    k_softmax<<<Bc * Hc * Sc / 4, 256, 0, stream>>>(pre_p, attn_p);
    k_pv<<<dim3(Sc / 128, Bc * Hc), 256, 0, stream>>>(attn_p, Vtb, Omid);
    k_proj<<<(Bc * Sc / 128) * (Ec / 64), 256, 0, stream>>>(Omid, Wo, bo, out_p);
}

// Round 5
// 213.802 us; speedup vs baseline: 1.0308x; 1.0308x over previous
//
#include <hip/hip_runtime.h>
#include <hip/hip_bf16.h>

using u16 = unsigned short;
typedef __attribute__((ext_vector_type(8))) short short8;   // 8 bf16 = 4 VGPR
typedef __attribute__((ext_vector_type(4))) float f32x4;

constexpr int Bc = 2, Sc = 1024, Ec = 1024, Hc = 16, HDc = 64;
constexpr float SCALE = 0.125f; // HD^-0.5

// f32 -> bf16 round-to-nearest-even
__device__ __forceinline__ u16 f2bf(float f) {
    union { float f; unsigned u; } v{f};
    unsigned r = v.u + 0x7FFF + ((v.u >> 16) & 1);
    return (u16)(r >> 16);
}
__device__ __forceinline__ float bf2f(u16 x) {
    union { unsigned u; float f; } v; v.u = ((unsigned)x) << 16; return v.f;
}

// ---------------------------------------------------------------------------
// P0b: V (B,H,S,HD panels) -> Vt[bh][d=64][S=1024] bf16 (transposed).
// grid (S/64, B*H), block 256.
// ---------------------------------------------------------------------------
__global__ __launch_bounds__(256) void k_convT(const float* __restrict__ V,
                                               u16* __restrict__ Vt) {
    __shared__ float tile[64][65];
    const int bh = blockIdx.y;
    const int k0 = blockIdx.x * 64;
    const float* Vp = V + (size_t)bh * Sc * HDc + (size_t)k0 * HDc;
    const int tid = threadIdx.x;

    #pragma unroll
    for (int it = 0; it < 4; ++it) {
        int idx = tid + it * 256;
        int k = idx >> 4, d4 = idx & 15;
        float4 v = *(const float4*)&Vp[k * HDc + d4 * 4];
        tile[d4 * 4 + 0][k] = v.x;
        tile[d4 * 4 + 1][k] = v.y;
        tile[d4 * 4 + 2][k] = v.z;
        tile[d4 * 4 + 3][k] = v.w;
    }
    __syncthreads();

    u16* Op = Vt + (size_t)bh * HDc * Sc + k0;
    #pragma unroll
    for (int it = 0; it < 4; ++it) {
        int idx = tid + it * 256;
        int d = idx >> 4, kq = idx & 15;
        u16 t[4];
        #pragma unroll
        for (int j = 0; j < 4; ++j) t[j] = f2bf(tile[d][kq * 4 + j]);
        *(uint2*)&Op[(size_t)d * Sc + kq * 4] = *(uint2*)t;
    }
}

// ---------------------------------------------------------------------------
// K1: scores + aid-mixer -> pre (f32). MFMA 16x16x32 bf16. (round-4, proven)
// ---------------------------------------------------------------------------
__global__ __launch_bounds__(256, 2) void k_scores(
    const float* __restrict__ Qf, const float* __restrict__ Kf,
    const float* __restrict__ aid, const float* __restrict__ mw,
    const float* __restrict__ mb, const float* __restrict__ ascale,
    float* __restrict__ pre)
{
    __shared__ u16 smem[2 * 128 * 64];        // Qs | Ks ; aliased as Rt later
    u16* Qs = smem;
    u16* Ks = smem + 128 * 64;

    const int bid = blockIdx.x;               // 0..2047
    const int xcd  = bid & 7;
    const int h    = (bid >> 3) & 15;
    const int tidx = (bid >> 7) * 8 + xcd;    // 0..127 = (b,qt,kt)
    const int kt = tidx & 7;
    const int qt = (tidx >> 3) & 7;
    const int b  = tidx >> 6;

    const float* Qp = Qf + (size_t)(b * Hc + h) * Sc * HDc + (size_t)qt * 128 * HDc;
    const float* Kp = Kf + (size_t)(b * Hc + h) * Sc * HDc + (size_t)kt * 128 * HDc;

    const int tid = threadIdx.x;

    #pragma unroll
    for (int it = 0; it < 4; ++it) {
        int idx = tid + it * 256;
        int r = idx >> 3, g = idx & 7;
        int gs = g ^ (r & 7);
        const float* qs = Qp + r * 64 + g * 8;
        const float* ks = Kp + r * 64 + g * 8;
        float4 qa = *(const float4*)qs, qb = *(const float4*)(qs + 4);
        float4 ka = *(const float4*)ks, kb2 = *(const float4*)(ks + 4);
        u16 tq[8] = {f2bf(qa.x), f2bf(qa.y), f2bf(qa.z), f2bf(qa.w),
                     f2bf(qb.x), f2bf(qb.y), f2bf(qb.z), f2bf(qb.w)};
        u16 tk[8] = {f2bf(ka.x), f2bf(ka.y), f2bf(ka.z), f2bf(ka.w),
                     f2bf(kb2.x), f2bf(kb2.y), f2bf(kb2.z), f2bf(kb2.w)};
        *(short8*)&Qs[r * 64 + gs * 8] = *(short8*)tq;
        *(short8*)&Ks[r * 64 + gs * 8] = *(short8*)tk;
    }
    __syncthreads();

    const int w = tid >> 6, lane = tid & 63;
    const int wq = (w >> 1) * 64, wk = (w & 1) * 64;
    const int lrow = lane & 15, lhi = lane >> 4;

    f32x4 acc[4][4] = {};
    #pragma unroll
    for (int ks = 0; ks < 2; ++ks) {
        short8 af[4], bfr[4];
        #pragma unroll
        for (int f = 0; f < 4; ++f) {
            int rq = wq + f * 16 + lrow;
            int g  = ks * 4 + lhi;
            af[f]  = *(const short8*)&Qs[rq * 64 + (g ^ (rq & 7)) * 8];
            int rk = wk + f * 16 + lrow;
            bfr[f] = *(const short8*)&Ks[rk * 64 + (g ^ (rk & 7)) * 8];
        }
        #pragma unroll
        for (int fq = 0; fq < 4; ++fq)
            #pragma unroll
            for (int fk = 0; fk < 4; ++fk)
                acc[fq][fk] = __builtin_amdgcn_mfma_f32_16x16x32_bf16(
                    af[fq], bfr[fk], acc[fq][fk], 0, 0, 0);
    }

    const float w0 = mw[h * 4 + 0], w1 = mw[h * 4 + 1];
    const float w2 = mw[h * 4 + 2], w3 = mw[h * 4 + 3];
    const float bias = mb[h];
    const float asc  = ascale[0];
    const size_t prebase = (size_t)(b * Hc + h) * Sc * Sc;

    float* Rt = (float*)smem;

    #pragma unroll
    for (int fq = 0; fq < 4; ++fq) {
        __syncthreads();
        #pragma unroll
        for (int r = 0; r < 4; ++r)
            #pragma unroll
            for (int fk = 0; fk < 4; ++fk)
                Rt[((w >> 1) * 16 + lhi * 4 + r) * 132 + wk + fk * 16 + lrow] =
                    acc[fq][fk][r];
        __syncthreads();

        const int rib = tid >> 3;
        const int c0  = (tid & 7) * 16;
        float s16[16];
        #pragma unroll
        for (int i = 0; i < 4; ++i)
            *(float4*)&s16[i * 4] = *(const float4*)&Rt[rib * 132 + c0 + i * 4];

        const int q  = qt * 128 + (rib >> 4) * 64 + fq * 16 + (rib & 15);
        const int kb = kt * 128 + c0;
        const float* ap = aid + ((size_t)(b * Sc + q) * Sc + kb) * 3;
        float a48[48];
        #pragma unroll
        for (int i = 0; i < 12; ++i)
            *(float4*)&a48[i * 4] = *(const float4*)&ap[i * 4];

        float o[16];
        #pragma unroll
        for (int j = 0; j < 16; ++j) {
            float s = s16[j] * SCALE;
            float m = s * w0 + a48[j * 3] * w1 + a48[j * 3 + 1] * w2
                    + a48[j * 3 + 2] * w3 + bias;
            o[j] = s + fmaxf(m, 0.f) * asc;
        }
        float* dst = pre + prebase + (size_t)q * Sc + kb;
        #pragma unroll
        for (int i = 0; i < 4; ++i)
            *(float4*)&dst[i * 4] = *(const float4*)&o[i * 4];
    }
}

// ---------------------------------------------------------------------------
// K2 (NEW): fused softmax + attn-write + PV.
// One block per (b,h,64-row q-band). 256 threads = 4 waves, wave owns 16 rows.
// LDS band holds the 64x1024 score row-band as bf16 (swizzled 16B granules).
// Phase A: read pre once, row-max, band store.
// Phase B: e=exp(s-m), l=rowsum, PV MFMA (V tiles double-buffered).
// Phase C: attn = e/l written coalesced; O = acc/l -> Omid bf16.
// ---------------------------------------------------------------------------
__global__ __launch_bounds__(256, 1) void k_spv(
    const float* __restrict__ pre, const u16* __restrict__ Vt,
    float* __restrict__ attn, u16* __restrict__ Omid)
{
    __shared__ u16 band[64 * 1024];       // 128 KiB
    __shared__ u16 Vs[2][64 * 64];        // 16 KiB

    const int bid = blockIdx.x;           // 0..511
    const int bh  = bid >> 4;
    const int qt  = (bid & 15) * 64;
    const int b   = bh >> 4, h = bh & 15;

    const int tid  = threadIdx.x;
    const int w    = tid >> 6, lane = tid & 63;
    const int lrow = lane & 15, lhi = lane >> 4;

    const int row = w * 16 + lrow;        // block-local q row (A-frag layout)
    const int sw  = row & 7;
    const float* prow = pre + ((size_t)bh * Sc + qt + row) * Sc;

    // ---------------- Phase A: stream pre, track max, fill band ----------
    float m = -1e30f;
    #pragma unroll
    for (int kt = 0; kt < 16; ++kt) {
        float s[16];
        const float* p0 = prow + kt * 64 + lhi * 8;
        *(float4*)&s[0]  = *(const float4*)p0;
        *(float4*)&s[4]  = *(const float4*)(p0 + 4);
        *(float4*)&s[8]  = *(const float4*)(p0 + 32);
        *(float4*)&s[12] = *(const float4*)(p0 + 36);
        u16 t[16];
        #pragma unroll
        for (int j = 0; j < 16; ++j) { m = fmaxf(m, s[j]); t[j] = f2bf(s[j]); }
        *(short8*)&band[row * 1024 + (kt * 8 + (lhi ^ sw)) * 8]       = *(short8*)&t[0];
        *(short8*)&band[row * 1024 + (kt * 8 + ((lhi + 4) ^ sw)) * 8] = *(short8*)&t[8];
    }
    m = fmaxf(m, __shfl_xor(m, 16));
    m = fmaxf(m, __shfl_xor(m, 32));

    // ---------------- Phase B: exp, row-sum, PV accumulate ---------------
    const u16* Vp = Vt + (size_t)bh * HDc * Sc;
    float l = 0.f;
    f32x4 acc[4] = {};

    #pragma unroll
    for (int it = 0; it < 2; ++it) {          // stage V tile 0
        int idx = tid + it * 256; int r = idx >> 3, g = idx & 7;
        *(short8*)&Vs[0][r * 64 + (g ^ (r & 7)) * 8] =
            *(const short8*)&Vp[(size_t)r * Sc + g * 8];
    }
    __syncthreads();

    for (int kt = 0; kt < 16; ++kt) {
        if (kt < 15) {                        // prefetch next V tile
            #pragma unroll
            for (int it = 0; it < 2; ++it) {
                int idx = tid + it * 256; int r = idx >> 3, g = idx & 7;
                *(short8*)&Vs[(kt + 1) & 1][r * 64 + (g ^ (r & 7)) * 8] =
                    *(const short8*)&Vp[(size_t)r * Sc + (kt + 1) * 64 + g * 8];
            }
        }
        short8 ra = *(const short8*)&band[row * 1024 + (kt * 8 + (lhi ^ sw)) * 8];
        short8 rb = *(const short8*)&band[row * 1024 + (kt * 8 + ((lhi + 4) ^ sw)) * 8];
        u16 ea[8], eb[8];
        float lsum = 0.f;
        #pragma unroll
        for (int j = 0; j < 8; ++j) {
            float va = __expf(bf2f((u16)ra[j]) - m); lsum += va; ea[j] = f2bf(va);
            float vb = __expf(bf2f((u16)rb[j]) - m); lsum += vb; eb[j] = f2bf(vb);
        }
        l += lsum;

        const u16* vbuf = Vs[kt & 1];
        short8 A0 = *(short8*)ea, A1 = *(short8*)eb;
        #pragma unroll
        for (int fd = 0; fd < 4; ++fd) {
            int rv = fd * 16 + lrow;
            short8 b0 = *(const short8*)&vbuf[rv * 64 + ((lhi) ^ (rv & 7)) * 8];
            short8 b1 = *(const short8*)&vbuf[rv * 64 + ((4 + lhi) ^ (rv & 7)) * 8];
            acc[fd] = __builtin_amdgcn_mfma_f32_16x16x32_bf16(A0, b0, acc[fd], 0, 0, 0);
            acc[fd] = __builtin_amdgcn_mfma_f32_16x16x32_bf16(A1, b1, acc[fd], 0, 0, 0);
        }
        __syncthreads();
    }
    l += __shfl_xor(l, 16);
    l += __shfl_xor(l, 32);

    // ---------------- Phase C: write attn (coalesced) and O --------------
    const int crow = w * 16 + (lane >> 2);
    const int swc  = crow & 7;
    const float mf  = __shfl(m, lane >> 2);
    const float inv = 1.f / __shfl(l, lane >> 2);
    float* arow = attn + ((size_t)bh * Sc + qt + crow) * Sc + (lane & 3) * 16;
    const int g0 = (lane & 3) * 2;
    #pragma unroll
    for (int kt = 0; kt < 16; ++kt) {
        short8 ra = *(const short8*)&band[crow * 1024 + (kt * 8 + (g0 ^ swc)) * 8];
        short8 rb = *(const short8*)&band[crow * 1024 + (kt * 8 + ((g0 + 1) ^ swc)) * 8];
        float o[16];
        #pragma unroll
        for (int j = 0; j < 8; ++j) {
            o[j]     = __expf(bf2f((u16)ra[j]) - mf) * inv;
            o[8 + j] = __expf(bf2f((u16)rb[j]) - mf) * inv;
        }
        #pragma unroll
        for (int i = 0; i < 4; ++i)
            *(float4*)&arow[kt * 64 + i * 4] = *(float4*)&o[i * 4];
    }

    #pragma unroll
    for (int reg = 0; reg < 4; ++reg) {
        const int rowO = w * 16 + lhi * 4 + reg;
        const float linv = 1.f / __shfl(l, lhi * 4 + reg);
        u16* orow = Omid + ((size_t)b * Sc + qt + rowO) * Ec + h * HDc;
        #pragma unroll
        for (int fd = 0; fd < 4; ++fd)
            orow[fd * 16 + lrow] = f2bf(acc[fd][reg] * linv);
    }
}

// ---------------------------------------------------------------------------
// K4: out = Omid @ Wo^T + bo (f32 out). A = Omid bf16, B = Wo f32->bf16.
// ---------------------------------------------------------------------------
__global__ __launch_bounds__(256, 2) void k_proj(
    const u16* __restrict__ Ob, const float* __restrict__ Wof,
    const float* __restrict__ bo, float* __restrict__ out)
{
    __shared__ u16 Xs[128 * 64];
    __shared__ u16 Ws[64 * 64];

    const int bid = blockIdx.x;
    const int mt = (bid >> 4) * 128;
    const int et = (bid & 15) * 64;

    const int tid = threadIdx.x;
    const int w = tid >> 6, lane = tid & 63;
    const int lrow = lane & 15, lhi = lane >> 4;

    f32x4 acc[2][4] = {};

    for (int kb = 0; kb < Ec; kb += 64) {
        #pragma unroll
        for (int it = 0; it < 4; ++it) {
            int idx = tid + it * 256;
            int r = idx >> 3, g = idx & 7;
            *(short8*)&Xs[r * 64 + (g ^ (r & 7)) * 8] =
                *(const short8*)&Ob[(size_t)(mt + r) * Ec + kb + g * 8];
        }
        #pragma unroll
        for (int it = 0; it < 2; ++it) {
            int idx = tid + it * 256;
            int r = idx >> 3, g = idx & 7;
            const float* sp = &Wof[(size_t)(et + r) * Ec + kb + g * 8];
            float4 x = *(const float4*)sp, y = *(const float4*)(sp + 4);
            u16 t[8] = {f2bf(x.x), f2bf(x.y), f2bf(x.z), f2bf(x.w),
                        f2bf(y.x), f2bf(y.y), f2bf(y.z), f2bf(y.w)};
            *(short8*)&Ws[r * 64 + (g ^ (r & 7)) * 8] = *(short8*)t;
        }
        __syncthreads();

        #pragma unroll
        for (int ks = 0; ks < 2; ++ks) {
            short8 af[2], bfr[4];
            int g = ks * 4 + lhi;
            #pragma unroll
            for (int fq = 0; fq < 2; ++fq) {
                int rq = w * 32 + fq * 16 + lrow;
                af[fq] = *(const short8*)&Xs[rq * 64 + (g ^ (rq & 7)) * 8];
            }
            #pragma unroll
            for (int fd = 0; fd < 4; ++fd) {
                int rv = fd * 16 + lrow;
                bfr[fd] = *(const short8*)&Ws[rv * 64 + (g ^ (rv & 7)) * 8];
            }
            #pragma unroll
            for (int fq = 0; fq < 2; ++fq)
                #pragma unroll
                for (int fd = 0; fd < 4; ++fd)
                    acc[fq][fd] = __builtin_amdgcn_mfma_f32_16x16x32_bf16(
                        af[fq], bfr[fd], acc[fq][fd], 0, 0, 0);
        }
        __syncthreads();
    }

    #pragma unroll
    for (int fq = 0; fq < 2; ++fq)
        #pragma unroll
        for (int r = 0; r < 4; ++r) {
            const int m = mt + w * 32 + fq * 16 + lhi * 4 + r;
            float* orow = out + (size_t)m * Ec + et;
            #pragma unroll
            for (int fd = 0; fd < 4; ++fd) {
                int e = fd * 16 + lrow;
                orow[e] = acc[fq][fd][r] + bo[et + e];
            }
        }
}

// ---------------------------------------------------------------------------
extern "C" void kernel_launch(void* const* d_in, const int* in_sizes, int n_in,
                              void* d_out, int out_size, void* d_ws, size_t ws_size,
                              hipStream_t stream) {
    const float* query  = (const float*)d_in[0];
    const float* key    = (const float*)d_in[1];
    const float* value  = (const float*)d_in[2];
    const float* aid    = (const float*)d_in[3];
    const float* mw     = (const float*)d_in[4];
    const float* mb     = (const float*)d_in[5];
    const float* Wo     = (const float*)d_in[6];
    const float* bo     = (const float*)d_in[7];
    const float* ascale = (const float*)d_in[8];

    float* out_p  = (float*)d_out;                       // (B,S,E)
    float* attn_p = out_p + (size_t)Bc * Sc * Ec;        // (B,H,S,S)
    float* pre_p  = attn_p + (size_t)Bc * Hc * Sc * Sc;  // (B,H,S,S)

    u16* Vtb  = (u16*)d_ws;                      // 2M elems (transposed V)
    u16* Omid = Vtb + (size_t)2 * 1024 * 1024;   // 2M elems

    k_convT<<<dim3(Sc / 64, Bc * Hc), 256, 0, stream>>>(value, Vtb);
    k_scores<<<2048, 256, 0, stream>>>(query, key, aid, mw, mb, ascale, pre_p);
    k_spv<<<512, 256, 0, stream>>>(pre_p, Vtb, attn_p, Omid);
    k_proj<<<(Bc * Sc / 128) * (Ec / 64), 256, 0, stream>>>(Omid, Wo, bo, out_p);
}

// Round 6
// 157.686 us; speedup vs baseline: 1.3977x; 1.3559x over previous
//
#include <hip/hip_runtime.h>
#include <hip/hip_bf16.h>

using u16 = unsigned short;
typedef __attribute__((ext_vector_type(8))) short short8;   // 8 bf16 = 4 VGPR
typedef __attribute__((ext_vector_type(4))) float f32x4;

constexpr int Bc = 2, Sc = 1024, Ec = 1024, Hc = 16, HDc = 64;
constexpr float SCALE = 0.125f; // HD^-0.5

// f32 -> bf16 round-to-nearest-even
__device__ __forceinline__ u16 f2bf(float f) {
    union { float f; unsigned u; } v{f};
    unsigned r = v.u + 0x7FFF + ((v.u >> 16) & 1);
    return (u16)(r >> 16);
}
__device__ __forceinline__ float bf2f(u16 x) {
    union { unsigned u; float f; } v; v.u = ((unsigned)x) << 16; return v.f;
}

// ---------------------------------------------------------------------------
// P0b: V (B,H,S,HD panels) -> Vt[bh][d=64][S=1024] bf16 (transposed).
// grid (S/64, B*H), block 256.
// ---------------------------------------------------------------------------
__global__ __launch_bounds__(256) void k_convT(const float* __restrict__ V,
                                               u16* __restrict__ Vt) {
    __shared__ float tile[64][65];
    const int bh = blockIdx.y;
    const int k0 = blockIdx.x * 64;
    const float* Vp = V + (size_t)bh * Sc * HDc + (size_t)k0 * HDc;
    const int tid = threadIdx.x;

    #pragma unroll
    for (int it = 0; it < 4; ++it) {
        int idx = tid + it * 256;
        int k = idx >> 4, d4 = idx & 15;
        float4 v = *(const float4*)&Vp[k * HDc + d4 * 4];
        tile[d4 * 4 + 0][k] = v.x;
        tile[d4 * 4 + 1][k] = v.y;
        tile[d4 * 4 + 2][k] = v.z;
        tile[d4 * 4 + 3][k] = v.w;
    }
    __syncthreads();

    u16* Op = Vt + (size_t)bh * HDc * Sc + k0;
    #pragma unroll
    for (int it = 0; it < 4; ++it) {
        int idx = tid + it * 256;
        int d = idx >> 4, kq = idx & 15;
        u16 t[4];
        #pragma unroll
        for (int j = 0; j < 4; ++j) t[j] = f2bf(tile[d][kq * 4 + j]);
        *(uint2*)&Op[(size_t)d * Sc + kq * 4] = *(uint2*)t;
    }
}

// ---------------------------------------------------------------------------
// K1 (NEW): scores + aid-mixer, ALL 16 HEADS per block.
// Block = (b, qt, kt) 64x64 tile. aid loaded ONCE into registers (C-layout
// matched), reused across the 16-head loop -> aid off HBM exactly once.
// grid 512 = B*16*16, block 256 = 4 waves; wave w owns rows w*16..+16.
// ---------------------------------------------------------------------------
__global__ __launch_bounds__(256, 2) void k_scores(
    const float* __restrict__ Qf, const float* __restrict__ Kf,
    const float* __restrict__ aid, const float* __restrict__ mw,
    const float* __restrict__ mb, const float* __restrict__ ascale,
    float* __restrict__ pre)
{
    __shared__ u16 Qs[64 * 64];
    __shared__ u16 Ks[64 * 64];

    const int bid = blockIdx.x;          // 0..511
    const int kt = bid & 15;
    const int qt = (bid >> 4) & 15;
    const int b  = bid >> 8;

    const int tid = threadIdx.x;
    const int w = tid >> 6, lane = tid & 63;
    const int lrow = lane & 15, lhi = lane >> 4;

    // aid -> regs. Positions match MFMA C-layout:
    //   rows q = qt*64 + w*16 + lhi*4 + r  (r=0..3)
    //   cols k = kt*64 + fk*16 + lrow      (fk=0..3)
    float a3[4][4][3];
    #pragma unroll
    for (int r = 0; r < 4; ++r) {
        const size_t qg = (size_t)(b * Sc + qt * 64 + w * 16 + lhi * 4 + r) * Sc;
        #pragma unroll
        for (int fk = 0; fk < 4; ++fk) {
            const float* ap = aid + (qg + kt * 64 + fk * 16 + lrow) * 3;
            float2 t2 = *(const float2*)ap;
            a3[r][fk][0] = t2.x; a3[r][fk][1] = t2.y; a3[r][fk][2] = ap[2];
        }
    }

    const float asc = ascale[0];
    const float* Qbase = Qf + ((size_t)b * Hc * Sc + qt * 64) * HDc;
    const float* Kbase = Kf + ((size_t)b * Hc * Sc + kt * 64) * HDc;

    for (int h = 0; h < Hc; ++h) {
        const float* Qp = Qbase + (size_t)h * Sc * HDc;
        const float* Kp = Kbase + (size_t)h * Sc * HDc;
        // stage 64x64 f32 -> bf16 swizzled (2 granules/thread each)
        #pragma unroll
        for (int it = 0; it < 2; ++it) {
            int idx = tid + it * 256;        // 0..511
            int r = idx >> 3, g = idx & 7;
            int gs = (g ^ (r & 7)) * 8;
            const float* qs = Qp + r * 64 + g * 8;
            const float* ks = Kp + r * 64 + g * 8;
            float4 qa = *(const float4*)qs, qb = *(const float4*)(qs + 4);
            float4 ka = *(const float4*)ks, kb = *(const float4*)(ks + 4);
            u16 tq[8] = {f2bf(qa.x), f2bf(qa.y), f2bf(qa.z), f2bf(qa.w),
                         f2bf(qb.x), f2bf(qb.y), f2bf(qb.z), f2bf(qb.w)};
            u16 tk[8] = {f2bf(ka.x), f2bf(ka.y), f2bf(ka.z), f2bf(ka.w),
                         f2bf(kb.x), f2bf(kb.y), f2bf(kb.z), f2bf(kb.w)};
            *(short8*)&Qs[r * 64 + gs] = *(short8*)tq;
            *(short8*)&Ks[r * 64 + gs] = *(short8*)tk;
        }
        __syncthreads();

        f32x4 acc[4] = {};
        #pragma unroll
        for (int ks2 = 0; ks2 < 2; ++ks2) {
            const int rq = w * 16 + lrow;
            short8 af = *(const short8*)&Qs[rq * 64 + ((ks2 * 4 + lhi) ^ (rq & 7)) * 8];
            #pragma unroll
            for (int fk = 0; fk < 4; ++fk) {
                const int rk = fk * 16 + lrow;
                short8 bf = *(const short8*)&Ks[rk * 64 + ((ks2 * 4 + lhi) ^ (rk & 7)) * 8];
                acc[fk] = __builtin_amdgcn_mfma_f32_16x16x32_bf16(af, bf, acc[fk], 0, 0, 0);
            }
        }

        const float w0 = mw[h * 4 + 0], w1 = mw[h * 4 + 1];
        const float w2 = mw[h * 4 + 2], w3 = mw[h * 4 + 3];
        const float bias = mb[h];
        float* prow0 = pre + ((size_t)(b * Hc + h) * Sc + qt * 64 + w * 16 + lhi * 4) * Sc
                     + kt * 64 + lrow;
        #pragma unroll
        for (int r = 0; r < 4; ++r) {
            #pragma unroll
            for (int fk = 0; fk < 4; ++fk) {
                float s = acc[fk][r] * SCALE;
                float mm = s * w0 + a3[r][fk][0] * w1 + a3[r][fk][1] * w2
                         + a3[r][fk][2] * w3 + bias;
                prow0[(size_t)r * Sc + fk * 16] = s + fmaxf(mm, 0.f) * asc;
            }
        }
        __syncthreads();   // protect Qs/Ks before next h
    }
}

// ---------------------------------------------------------------------------
// K2: fused softmax + attn-write + PV. 512 threads = 8 waves (2/SIMD).
// One block per (b,h,64-row q-band). Band: 64x1024 bf16 scores in LDS.
// Phase A: stream pre once, row-max, fill band.
// Phase B: waves split (row-frag rf x d-half dh); e=exp(s-m), l, PV MFMA.
// Phase C: attn = e/l coalesced; O = acc/l -> Omid bf16.
// ---------------------------------------------------------------------------
__global__ __launch_bounds__(512, 1) void k_spv(
    const float* __restrict__ pre, const u16* __restrict__ Vt,
    float* __restrict__ attn, u16* __restrict__ Omid)
{
    __shared__ u16 band[64 * 1024];       // 128 KiB
    __shared__ u16 Vs[2][64 * 64];        // 16 KiB
    __shared__ float s_m[64], s_l[64];

    const int bid = blockIdx.x;           // 0..511
    const int bh  = bid >> 4;
    const int qt  = (bid & 15) * 64;
    const int b   = bh >> 4, h = bh & 15;

    const int tid  = threadIdx.x;
    const int w    = tid >> 6, lane = tid & 63;
    const int lrow = lane & 15, lhi = lane >> 4;

    // ---------------- Phase A: stream pre, track max, fill band ----------
    const int arow_i = tid >> 3;          // 0..63
    const int sub    = tid & 7;
    const int asw    = arow_i & 7;
    const float* prow = pre + ((size_t)bh * Sc + qt + arow_i) * Sc;
    float m = -1e30f;
    #pragma unroll 4
    for (int kt = 0; kt < 16; ++kt) {
        const float* p0 = prow + kt * 64 + sub * 8;
        float s[8];
        *(float4*)&s[0] = *(const float4*)p0;
        *(float4*)&s[4] = *(const float4*)(p0 + 4);
        u16 t[8];
        #pragma unroll
        for (int j = 0; j < 8; ++j) { m = fmaxf(m, s[j]); t[j] = f2bf(s[j]); }
        *(short8*)&band[arow_i * 1024 + (kt * 8 + (sub ^ asw)) * 8] = *(short8*)t;
    }
    m = fmaxf(m, __shfl_xor(m, 1));
    m = fmaxf(m, __shfl_xor(m, 2));
    m = fmaxf(m, __shfl_xor(m, 4));
    if (sub == 0) s_m[arow_i] = m;

    // stage V tile 0 (1 granule/thread)
    const u16* Vp = Vt + (size_t)bh * HDc * Sc;
    {
        int r = tid >> 3, g = tid & 7;
        *(short8*)&Vs[0][r * 64 + (g ^ (r & 7)) * 8] =
            *(const short8*)&Vp[(size_t)r * Sc + g * 8];
    }
    __syncthreads();

    // ---------------- Phase B: exp, row-sum, PV accumulate ---------------
    const int rf = w >> 1, dh = w & 1;    // row-frag 0..3, d-half 0..1
    const int brow = rf * 16 + lrow;
    const int bsw  = brow & 7;
    const float mreg = s_m[brow];
    float l = 0.f;
    f32x4 acc[2] = {};

    for (int kt = 0; kt < 16; ++kt) {
        if (kt < 15) {                    // prefetch next V tile
            int r = tid >> 3, g = tid & 7;
            *(short8*)&Vs[(kt + 1) & 1][r * 64 + (g ^ (r & 7)) * 8] =
                *(const short8*)&Vp[(size_t)r * Sc + (kt + 1) * 64 + g * 8];
        }
        short8 ra = *(const short8*)&band[brow * 1024 + (kt * 8 + (lhi ^ bsw)) * 8];
        short8 rb = *(const short8*)&band[brow * 1024 + (kt * 8 + ((lhi + 4) ^ bsw)) * 8];
        u16 ea[8], eb[8];
        #pragma unroll
        for (int j = 0; j < 8; ++j) {
            float va = __expf(bf2f((u16)ra[j]) - mreg); l += va; ea[j] = f2bf(va);
            float vb = __expf(bf2f((u16)rb[j]) - mreg); l += vb; eb[j] = f2bf(vb);
        }
        const u16* vbuf = Vs[kt & 1];
        short8 A0 = *(short8*)ea, A1 = *(short8*)eb;
        #pragma unroll
        for (int fd = 0; fd < 2; ++fd) {
            int rv = dh * 32 + fd * 16 + lrow;
            short8 b0 = *(const short8*)&vbuf[rv * 64 + ((lhi) ^ (rv & 7)) * 8];
            short8 b1 = *(const short8*)&vbuf[rv * 64 + ((lhi + 4) ^ (rv & 7)) * 8];
            acc[fd] = __builtin_amdgcn_mfma_f32_16x16x32_bf16(A0, b0, acc[fd], 0, 0, 0);
            acc[fd] = __builtin_amdgcn_mfma_f32_16x16x32_bf16(A1, b1, acc[fd], 0, 0, 0);
        }
        __syncthreads();
    }
    l += __shfl_xor(l, 16);
    l += __shfl_xor(l, 32);
    if (dh == 0 && lhi == 0) s_l[brow] = l;
    __syncthreads();

    // ---------------- Phase C: write attn (coalesced) and O --------------
    const float mf  = s_m[arow_i];
    const float inv = 1.f / s_l[arow_i];
    float* arow = attn + ((size_t)bh * Sc + qt + arow_i) * Sc;
    #pragma unroll 4
    for (int kt = 0; kt < 16; ++kt) {
        short8 ra = *(const short8*)&band[arow_i * 1024 + (kt * 8 + (sub ^ asw)) * 8];
        float o[8];
        #pragma unroll
        for (int j = 0; j < 8; ++j) o[j] = __expf(bf2f((u16)ra[j]) - mf) * inv;
        *(float4*)&arow[kt * 64 + sub * 8]     = *(float4*)&o[0];
        *(float4*)&arow[kt * 64 + sub * 8 + 4] = *(float4*)&o[4];
    }

    #pragma unroll
    for (int reg = 0; reg < 4; ++reg) {
        const int rowO = rf * 16 + lhi * 4 + reg;
        const float linv = 1.f / s_l[rowO];
        u16* orow = Omid + ((size_t)b * Sc + qt + rowO) * Ec + h * HDc + dh * 32;
        #pragma unroll
        for (int fd = 0; fd < 2; ++fd)
            orow[fd * 16 + lrow] = f2bf(acc[fd][reg] * linv);
    }
}

// ---------------------------------------------------------------------------
// K4: out = Omid @ Wo^T + bo (f32 out). A = Omid bf16, B = Wo f32->bf16.
// ---------------------------------------------------------------------------
__global__ __launch_bounds__(256, 2) void k_proj(
    const u16* __restrict__ Ob, const float* __restrict__ Wof,
    const float* __restrict__ bo, float* __restrict__ out)
{
    __shared__ u16 Xs[128 * 64];
    __shared__ u16 Ws[64 * 64];

    const int bid = blockIdx.x;
    const int mt = (bid >> 4) * 128;
    const int et = (bid & 15) * 64;

    const int tid = threadIdx.x;
    const int w = tid >> 6, lane = tid & 63;
    const int lrow = lane & 15, lhi = lane >> 4;

    f32x4 acc[2][4] = {};

    for (int kb = 0; kb < Ec; kb += 64) {
        #pragma unroll
        for (int it = 0; it < 4; ++it) {
            int idx = tid + it * 256;
            int r = idx >> 3, g = idx & 7;
            *(short8*)&Xs[r * 64 + (g ^ (r & 7)) * 8] =
                *(const short8*)&Ob[(size_t)(mt + r) * Ec + kb + g * 8];
        }
        #pragma unroll
        for (int it = 0; it < 2; ++it) {
            int idx = tid + it * 256;
            int r = idx >> 3, g = idx & 7;
            const float* sp = &Wof[(size_t)(et + r) * Ec + kb + g * 8];
            float4 x = *(const float4*)sp, y = *(const float4*)(sp + 4);
            u16 t[8] = {f2bf(x.x), f2bf(x.y), f2bf(x.z), f2bf(x.w),
                        f2bf(y.x), f2bf(y.y), f2bf(y.z), f2bf(y.w)};
            *(short8*)&Ws[r * 64 + (g ^ (r & 7)) * 8] = *(short8*)t;
        }
        __syncthreads();

        #pragma unroll
        for (int ks = 0; ks < 2; ++ks) {
            short8 af[2], bfr[4];
            int g = ks * 4 + lhi;
            #pragma unroll
            for (int fq = 0; fq < 2; ++fq) {
                int rq = w * 32 + fq * 16 + lrow;
                af[fq] = *(const short8*)&Xs[rq * 64 + (g ^ (rq & 7)) * 8];
            }
            #pragma unroll
            for (int fd = 0; fd < 4; ++fd) {
                int rv = fd * 16 + lrow;
                bfr[fd] = *(const short8*)&Ws[rv * 64 + (g ^ (rv & 7)) * 8];
            }
            #pragma unroll
            for (int fq = 0; fq < 2; ++fq)
                #pragma unroll
                for (int fd = 0; fd < 4; ++fd)
                    acc[fq][fd] = __builtin_amdgcn_mfma_f32_16x16x32_bf16(
                        af[fq], bfr[fd], acc[fq][fd], 0, 0, 0);
        }
        __syncthreads();
    }

    #pragma unroll
    for (int fq = 0; fq < 2; ++fq)
        #pragma unroll
        for (int r = 0; r < 4; ++r) {
            const int m = mt + w * 32 + fq * 16 + lhi * 4 + r;
            float* orow = out + (size_t)m * Ec + et;
            #pragma unroll
            for (int fd = 0; fd < 4; ++fd) {
                int e = fd * 16 + lrow;
                orow[e] = acc[fq][fd][r] + bo[et + e];
            }
        }
}

// ---------------------------------------------------------------------------
extern "C" void kernel_launch(void* const* d_in, const int* in_sizes, int n_in,
                              void* d_out, int out_size, void* d_ws, size_t ws_size,
                              hipStream_t stream) {
    const float* query  = (const float*)d_in[0];
    const float* key    = (const float*)d_in[1];
    const float* value  = (const float*)d_in[2];
    const float* aid    = (const float*)d_in[3];
    const float* mw     = (const float*)d_in[4];
    const float* mb     = (const float*)d_in[5];
    const float* Wo     = (const float*)d_in[6];
    const float* bo     = (const float*)d_in[7];
    const float* ascale = (const float*)d_in[8];

    float* out_p  = (float*)d_out;                       // (B,S,E)
    float* attn_p = out_p + (size_t)Bc * Sc * Ec;        // (B,H,S,S)
    float* pre_p  = attn_p + (size_t)Bc * Hc * Sc * Sc;  // (B,H,S,S)

    u16* Vtb  = (u16*)d_ws;                      // 2M elems (transposed V)
    u16* Omid = Vtb + (size_t)2 * 1024 * 1024;   // 2M elems

    k_convT<<<dim3(Sc / 64, Bc * Hc), 256, 0, stream>>>(value, Vtb);
    k_scores<<<Bc * 16 * 16, 256, 0, stream>>>(query, key, aid, mw, mb, ascale, pre_p);
    k_spv<<<512, 512, 0, stream>>>(pre_p, Vtb, attn_p, Omid);
    k_proj<<<(Bc * Sc / 128) * (Ec / 64), 256, 0, stream>>>(Omid, Wo, bo, out_p);
}